// Round 4
// baseline (514.851 us; speedup 1.0000x reference)
//
#include <hip/hip_runtime.h>

#define NN 50000
#define EE 800000
#define HH 128
#define CC 10
#define GG 128

typedef __attribute__((ext_vector_type(8))) short short8;
typedef __attribute__((ext_vector_type(4))) float f32x4;

// ---------- bf16 helpers (RNE) ----------
__device__ __forceinline__ ushort f2b(float f) {
    union { float f; uint u; } x; x.f = f;
    uint u = x.u;
    uint r = (u + 0x7fffu + ((u >> 16) & 1u)) >> 16;
    return (ushort)r;
}
__device__ __forceinline__ float lo2f(uint v) {
    union { uint u; float f; } x; x.u = v << 16; return x.f;
}
__device__ __forceinline__ float hi2f(uint v) {
    union { uint u; float f; } x; x.u = v & 0xffff0000u; return x.f;
}

// ---------------- CSR build ----------------

__global__ void count_kernel(const int* __restrict__ dst, int* cnt) {
    int e = blockIdx.x * 256 + threadIdx.x;
    if (e < EE) atomicAdd(&cnt[dst[e]], 1);
}

__global__ void scan1_kernel(const int* cnt, int* bsum) {
    __shared__ int s[512];
    int n = blockIdx.x * 512 + threadIdx.x;
    s[threadIdx.x] = (n < NN) ? cnt[n] : 0;
    __syncthreads();
    for (int off = 256; off > 0; off >>= 1) {
        if (threadIdx.x < off) s[threadIdx.x] += s[threadIdx.x + off];
        __syncthreads();
    }
    if (threadIdx.x == 0) bsum[blockIdx.x] = s[0];
}

__global__ void scan2_kernel(int* bsum, int* rowptr, int nb) {
    __shared__ int s[128];
    int t = threadIdx.x;
    int v = (t < nb) ? bsum[t] : 0;
    s[t] = v;
    __syncthreads();
    for (int off = 1; off < 128; off <<= 1) {
        int tt = (t >= off) ? s[t - off] : 0;
        __syncthreads();
        s[t] += tt;
        __syncthreads();
    }
    if (t < nb) bsum[t] = s[t] - v;   // exclusive block offsets
    if (t == 0) rowptr[NN] = EE;
}

__global__ void scan3_kernel(const int* cnt, const int* bsum, int* rowptr, int* cursor) {
    __shared__ int s[512];
    int t = threadIdx.x;
    int n = blockIdx.x * 512 + t;
    int v = (n < NN) ? cnt[n] : 0;
    s[t] = v;
    __syncthreads();
    for (int off = 1; off < 512; off <<= 1) {
        int tt = (t >= off) ? s[t - off] : 0;
        __syncthreads();
        s[t] += tt;
        __syncthreads();
    }
    int excl = s[t] - v + bsum[blockIdx.x];
    if (n < NN) { rowptr[n] = excl; cursor[n] = excl; }
}

__global__ void fill_kernel(const int* __restrict__ src, const int* __restrict__ dst,
                            int* cursor, int* eidx) {
    int e = blockIdx.x * 256 + threadIdx.x;
    if (e < EE) {
        int p = atomicAdd(&cursor[dst[e]], 1);
        eidx[p] = src[e];
    }
}

// ---------------- conversions ----------------

__global__ __launch_bounds__(256) void f2b_kernel(const float* __restrict__ in,
                                                  ushort* __restrict__ out, int n4) {
    int i = blockIdx.x * 256 + threadIdx.x;
    if (i < n4) {
        float4 v = ((const float4*)in)[i];
        ushort4 o;
        o.x = f2b(v.x); o.y = f2b(v.y); o.z = f2b(v.z); o.w = f2b(v.w);
        ((ushort4*)out)[i] = o;
    }
}

// transpose-convert the 6 MLP weights: wt[mi][n][k] = bf16(w_mi[k][n])
__global__ __launch_bounds__(256) void wconv_kernel(const float* w0, const float* w1,
                                                    const float* w2, const float* w3,
                                                    const float* w4, const float* w5,
                                                    ushort* __restrict__ wt) {
    const float* src;
    switch (blockIdx.y) {
        case 0: src = w0; break; case 1: src = w1; break;
        case 2: src = w2; break; case 3: src = w3; break;
        case 4: src = w4; break; default: src = w5; break;
    }
    int idx = blockIdx.x * 256 + threadIdx.x;   // 0..16383
    int n = idx >> 7, k = idx & 127;
    wt[blockIdx.y * 16384 + n * 128 + k] = f2b(src[k * 128 + n]);
}

// ---------------- fused layer: gather + combine + 2-GEMM MLP ----------------
// out = relu(relu(((1+eps)h + segsum(h[src]))@W1+b1)@W2+b2)
// Block: 64 rows x 128 cols, 256 threads (4 waves). Wave w gathers local rows
// [w*16, w*16+16): half-wave split (lanes 0-31 even edges, 32-63 odd edges),
// uint2 (4 bf16 cols) per lane, cross-half reduce via shfl_xor(32).
// MFMA with W^T as A-operand: lane packs 4 consecutive out cols -> 8B stores.

__global__ __launch_bounds__(256) void fused_layer(const ushort* __restrict__ hin,
                                                   const int* __restrict__ rowptr,
                                                   const int* __restrict__ eidx,
                                                   const ushort* __restrict__ wt1,  // [n][k]
                                                   const ushort* __restrict__ wt2,  // [n][k]
                                                   const float* __restrict__ b1,
                                                   const float* __restrict__ b2,
                                                   const float* __restrict__ epsp, int layer,
                                                   ushort* __restrict__ out, int nrows) {
    __shared__ __align__(16) ushort xs[64][136];
    __shared__ __align__(16) ushort hs[64][136];
    const int tid = threadIdx.x;
    const int lane = tid & 63, w = tid >> 6;
    const int row0 = blockIdx.x * 64;
    const int l15 = lane & 15, lhi = lane >> 4;
    const int half = lane >> 5, li = lane & 31;

    const float eps1 = 1.0f + epsp[layer];

    // ---- gather + combine -> xs ----
    for (int r = 0; r < 16; ++r) {
        int rl = w * 16 + r;
        int node = row0 + rl;
        float c0 = 0.f, c1 = 0.f, c2 = 0.f, c3 = 0.f;
        if (node < nrows) {
            int beg = rowptr[node], end = rowptr[node + 1];
            int i = beg + half;
            for (; i + 2 < end; i += 4) {
                int s0 = eidx[i], s1 = eidx[i + 2];
                uint2 v0 = *(const uint2*)(hin + (size_t)s0 * HH + li * 4);
                uint2 v1 = *(const uint2*)(hin + (size_t)s1 * HH + li * 4);
                c0 += lo2f(v0.x) + lo2f(v1.x);
                c1 += hi2f(v0.x) + hi2f(v1.x);
                c2 += lo2f(v0.y) + lo2f(v1.y);
                c3 += hi2f(v0.y) + hi2f(v1.y);
            }
            if (i < end) {
                int s0 = eidx[i];
                uint2 v0 = *(const uint2*)(hin + (size_t)s0 * HH + li * 4);
                c0 += lo2f(v0.x); c1 += hi2f(v0.x);
                c2 += lo2f(v0.y); c3 += hi2f(v0.y);
            }
        }
        // cross-half reduce (both halves end with the full sum)
        c0 += __shfl_xor(c0, 32);
        c1 += __shfl_xor(c1, 32);
        c2 += __shfl_xor(c2, 32);
        c3 += __shfl_xor(c3, 32);
        if (half == 0) {
            ushort4 o;
            if (node < nrows) {
                uint2 xo = *(const uint2*)(hin + (size_t)node * HH + li * 4);
                o.x = f2b(eps1 * lo2f(xo.x) + c0);
                o.y = f2b(eps1 * hi2f(xo.x) + c1);
                o.z = f2b(eps1 * lo2f(xo.y) + c2);
                o.w = f2b(eps1 * hi2f(xo.y) + c3);
            } else {
                o.x = 0; o.y = 0; o.z = 0; o.w = 0;
            }
            *(ushort4*)&xs[rl][li * 4] = o;
        }
    }

    // ---- load W1 fragments (L2-hot) ----
    short8 a1[2][4];
#pragma unroll
    for (int fa = 0; fa < 2; ++fa)
#pragma unroll
        for (int kt = 0; kt < 4; ++kt) {
            int n = w * 32 + fa * 16 + l15;
            int k = kt * 32 + lhi * 8;
            a1[fa][kt] = *(const short8*)(wt1 + n * HH + k);
        }
    __syncthreads();

    // ---- GEMM1 ----
    f32x4 acc[2][4];
#pragma unroll
    for (int fa = 0; fa < 2; ++fa)
#pragma unroll
        for (int fb = 0; fb < 4; ++fb) acc[fa][fb] = (f32x4)(0.f);
#pragma unroll
    for (int kt = 0; kt < 4; ++kt) {
        short8 bfr[4];
#pragma unroll
        for (int fb = 0; fb < 4; ++fb)
            bfr[fb] = *(const short8*)&xs[fb * 16 + l15][kt * 32 + lhi * 8];
#pragma unroll
        for (int fa = 0; fa < 2; ++fa)
#pragma unroll
            for (int fb = 0; fb < 4; ++fb)
                acc[fa][fb] = __builtin_amdgcn_mfma_f32_16x16x32_bf16(a1[fa][kt], bfr[fb],
                                                                     acc[fa][fb], 0, 0, 0);
    }

    // hidden = relu(acc + b1) -> bf16 -> hs
#pragma unroll
    for (int fa = 0; fa < 2; ++fa) {
        int nb = w * 32 + fa * 16 + lhi * 4;
        float4 bv = *(const float4*)(b1 + nb);
#pragma unroll
        for (int fb = 0; fb < 4; ++fb) {
            ushort4 o;
            o.x = f2b(fmaxf(acc[fa][fb][0] + bv.x, 0.f));
            o.y = f2b(fmaxf(acc[fa][fb][1] + bv.y, 0.f));
            o.z = f2b(fmaxf(acc[fa][fb][2] + bv.z, 0.f));
            o.w = f2b(fmaxf(acc[fa][fb][3] + bv.w, 0.f));
            *(ushort4*)&hs[fb * 16 + l15][nb] = o;
        }
    }

    // ---- load W2 fragments (straddles the barrier) ----
    short8 a2[2][4];
#pragma unroll
    for (int fa = 0; fa < 2; ++fa)
#pragma unroll
        for (int kt = 0; kt < 4; ++kt) {
            int n = w * 32 + fa * 16 + l15;
            int k = kt * 32 + lhi * 8;
            a2[fa][kt] = *(const short8*)(wt2 + n * HH + k);
        }
    __syncthreads();

    // ---- GEMM2 ----
#pragma unroll
    for (int fa = 0; fa < 2; ++fa)
#pragma unroll
        for (int fb = 0; fb < 4; ++fb) acc[fa][fb] = (f32x4)(0.f);
#pragma unroll
    for (int kt = 0; kt < 4; ++kt) {
        short8 bfr[4];
#pragma unroll
        for (int fb = 0; fb < 4; ++fb)
            bfr[fb] = *(const short8*)&hs[fb * 16 + l15][kt * 32 + lhi * 8];
#pragma unroll
        for (int fa = 0; fa < 2; ++fa)
#pragma unroll
            for (int fb = 0; fb < 4; ++fb)
                acc[fa][fb] = __builtin_amdgcn_mfma_f32_16x16x32_bf16(a2[fa][kt], bfr[fb],
                                                                     acc[fa][fb], 0, 0, 0);
    }

    // epilogue: out = relu(acc + b2) -> bf16 global
#pragma unroll
    for (int fa = 0; fa < 2; ++fa) {
        int nb = w * 32 + fa * 16 + lhi * 4;
        float4 bv = *(const float4*)(b2 + nb);
#pragma unroll
        for (int fb = 0; fb < 4; ++fb) {
            int m = row0 + fb * 16 + l15;
            if (m < nrows) {
                ushort4 o;
                o.x = f2b(fmaxf(acc[fa][fb][0] + bv.x, 0.f));
                o.y = f2b(fmaxf(acc[fa][fb][1] + bv.y, 0.f));
                o.z = f2b(fmaxf(acc[fa][fb][2] + bv.z, 0.f));
                o.w = f2b(fmaxf(acc[fa][fb][3] + bv.w, 0.f));
                *(ushort4*)(out + (size_t)m * HH + nb) = o;
            }
        }
    }
}

// ---------------- sum pooling: 64 nodes/block, 256 threads, register accumulate ------

__global__ __launch_bounds__(256) void pool_kernel(const ushort* __restrict__ h,
                                                   const int* __restrict__ gid,
                                                   float* hg) {
    int j = threadIdx.x & 63;        // uint col-pair index
    int r0 = threadIdx.x >> 6;       // 0..3
    int n0 = blockIdx.x * 64;
    float ax = 0.f, ay = 0.f;
    int gcur = -1;
#pragma unroll
    for (int i = 0; i < 16; ++i) {
        int n = n0 + r0 + i * 4;
        if (n >= NN) break;
        int g = gid[n];
        if (g != gcur) {
            if (gcur >= 0) {
                atomicAdd(&hg[gcur * HH + 2 * j], ax);
                atomicAdd(&hg[gcur * HH + 2 * j + 1], ay);
            }
            gcur = g; ax = 0.f; ay = 0.f;
        }
        uint v = *(const uint*)(h + (size_t)n * HH + 2 * j);
        ax += lo2f(v); ay += hi2f(v);
    }
    if (gcur >= 0) {
        atomicAdd(&hg[gcur * HH + 2 * j], ax);
        atomicAdd(&hg[gcur * HH + 2 * j + 1], ay);
    }
}

// ---------------- classifier head (fp32) ----------------

__global__ __launch_bounds__(128) void classify_kernel(const float* __restrict__ hg,
                                                       const float* __restrict__ wc1,
                                                       const float* __restrict__ bc1,
                                                       const float* __restrict__ wc2,
                                                       const float* __restrict__ bc2,
                                                       float* __restrict__ out) {
    __shared__ float xrow[HH];
    __shared__ float trow[HH];
    int g = blockIdx.x, j = threadIdx.x;
    xrow[j] = hg[g * HH + j];
    __syncthreads();
    float s = bc1[j];
#pragma unroll 8
    for (int k = 0; k < HH; ++k) s += xrow[k] * wc1[k * HH + j];
    trow[j] = fmaxf(s, 0.f);
    __syncthreads();
    if (j < CC) {
        float o = bc2[j];
#pragma unroll 8
        for (int k = 0; k < HH; ++k) o += trow[k] * wc2[k * CC + j];
        out[g * CC + j] = o;
    }
}

extern "C" void kernel_launch(void* const* d_in, const int* in_sizes, int n_in,
                              void* d_out, int out_size, void* d_ws, size_t ws_size,
                              hipStream_t stream) {
    const float* features = (const float*)d_in[0];
    const int* src = (const int*)d_in[1];
    const int* dst = (const int*)d_in[2];
    const int* gid = (const int*)d_in[3];
    const float* eps = (const float*)d_in[4];
    const float* w1[3] = {(const float*)d_in[5], (const float*)d_in[9], (const float*)d_in[13]};
    const float* b1[3] = {(const float*)d_in[6], (const float*)d_in[10], (const float*)d_in[14]};
    const float* w2[3] = {(const float*)d_in[7], (const float*)d_in[11], (const float*)d_in[15]};
    const float* b2[3] = {(const float*)d_in[8], (const float*)d_in[12], (const float*)d_in[16]};
    const float* wc1 = (const float*)d_in[17];
    const float* bc1 = (const float*)d_in[18];
    const float* wc2 = (const float*)d_in[19];
    const float* bc2 = (const float*)d_in[20];
    float* outp = (float*)d_out;

    char* ws = (char*)d_ws;
    size_t off = 0;
    auto alloc = [&](size_t bytes) {
        void* p = ws + off;
        off += (bytes + 255) & ~(size_t)255;
        return p;
    };
    int* rowptr = (int*)alloc((NN + 1) * sizeof(int));
    int* cursor = (int*)alloc(NN * sizeof(int));
    int* eidx = (int*)alloc(EE * sizeof(int));
    int* bsum = (int*)alloc(128 * sizeof(int));
    ushort* hb0 = (ushort*)alloc((size_t)NN * HH * 2);    // features bf16
    ushort* hb1 = (ushort*)alloc((size_t)NN * HH * 2);    // layer h bf16
    ushort* hb2 = (ushort*)alloc((size_t)NN * HH * 2);    // ping-pong layer h
    ushort* wtb = (ushort*)alloc(6 * 16384 * 2);          // transposed bf16 weights
    float* hg = (float*)alloc(GG * HH * sizeof(float));

    const int NB = (NN + 511) / 512;  // 98

    // CSR build
    hipMemsetAsync(cursor, 0, NN * sizeof(int), stream);
    count_kernel<<<(EE + 255) / 256, 256, 0, stream>>>(dst, cursor);
    scan1_kernel<<<NB, 512, 0, stream>>>(cursor, bsum);
    scan2_kernel<<<1, 128, 0, stream>>>(bsum, rowptr, NB);
    scan3_kernel<<<NB, 512, 0, stream>>>(cursor, bsum, rowptr, cursor);
    fill_kernel<<<(EE + 255) / 256, 256, 0, stream>>>(src, dst, cursor, eidx);

    // conversions
    f2b_kernel<<<(NN * HH / 4 + 255) / 256, 256, 0, stream>>>(features, hb0, NN * HH / 4);
    dim3 wg(64, 6);
    wconv_kernel<<<wg, 256, 0, stream>>>(w1[0], w2[0], w1[1], w2[1], w1[2], w2[2], wtb);
    // wtb layout: [0]=w1_0, [1]=w2_0, [2]=w1_1, [3]=w2_1, [4]=w1_2, [5]=w2_2

    const int GB = (NN + 63) / 64;  // 782

    // 3 GIN layers (fused gather + combine + 2-GEMM MLP)
    const ushort* hin = hb0;
    ushort* houts[3] = {hb1, hb2, hb1};
    for (int i = 0; i < 3; ++i) {
        fused_layer<<<GB, 256, 0, stream>>>(hin, rowptr, eidx,
                                            wtb + (2 * i) * 16384, wtb + (2 * i + 1) * 16384,
                                            b1[i], b2[i], eps, i, houts[i], NN);
        hin = houts[i];
    }

    // pooling + classifier
    hipMemsetAsync(hg, 0, GG * HH * sizeof(float), stream);
    pool_kernel<<<(NN + 63) / 64, 256, 0, stream>>>(hb1, gid, hg);
    classify_kernel<<<GG, 128, 0, stream>>>(hg, wc1, bc1, wc2, bc2, outp);
}